// Round 6
// baseline (35446.747 us; speedup 1.0000x reference)
//
#include <hip/hip_runtime.h>
#include <math.h>
#include <stdint.h>

// Problem constants
#define B_ROWS 512
#define H_UNITS 16384
#define K_IN 2048
#define K_SEL 64

// ---------------------------------------------------------------------------
// Kernel 1: encoding = inputs @ W^T  (fp32 mul, 64-chunk fp32 acc, fp64 chunk sum)
// C[512][16384] = A[512][2048] . W[16384][2048]^T   -- C lives in d_out
// ---------------------------------------------------------------------------
__global__ __launch_bounds__(256) void gemm_kernel(const float* __restrict__ A,
                                                   const float* __restrict__ W,
                                                   float* __restrict__ C) {
  __shared__ __align__(16) float As[64][68];
  __shared__ __align__(16) float Bs[64][68];
  const int tid = threadIdx.x;
  const int tx = tid & 15, ty = tid >> 4;
  const int bm = blockIdx.y * 64, bn = blockIdx.x * 64;

  double accd[16];
#pragma unroll
  for (int i = 0; i < 16; ++i) accd[i] = 0.0;

  const float* Ab = A + (size_t)bm * K_IN;
  const float* Wb = W + (size_t)bn * K_IN;

  for (int k0 = 0; k0 < K_IN; k0 += 64) {
#pragma unroll
    for (int p = 0; p < 4; ++p) {
      int id = p * 256 + tid;
      int m = id >> 4;
      int kq = (id & 15) << 2;
      float4 a = *reinterpret_cast<const float4*>(Ab + (size_t)m * K_IN + k0 + kq);
      As[kq + 0][m] = a.x; As[kq + 1][m] = a.y; As[kq + 2][m] = a.z; As[kq + 3][m] = a.w;
      float4 b = *reinterpret_cast<const float4*>(Wb + (size_t)m * K_IN + k0 + kq);
      Bs[kq + 0][m] = b.x; Bs[kq + 1][m] = b.y; Bs[kq + 2][m] = b.z; Bs[kq + 3][m] = b.w;
    }
    __syncthreads();

    float accf[16];
#pragma unroll
    for (int i = 0; i < 16; ++i) accf[i] = 0.0f;

#pragma unroll 16
    for (int kk = 0; kk < 64; ++kk) {
      float4 av = *reinterpret_cast<const float4*>(&As[kk][ty << 2]);
      float4 bv = *reinterpret_cast<const float4*>(&Bs[kk][tx << 2]);
      accf[0]  += av.x * bv.x; accf[1]  += av.x * bv.y; accf[2]  += av.x * bv.z; accf[3]  += av.x * bv.w;
      accf[4]  += av.y * bv.x; accf[5]  += av.y * bv.y; accf[6]  += av.y * bv.z; accf[7]  += av.y * bv.w;
      accf[8]  += av.z * bv.x; accf[9]  += av.z * bv.y; accf[10] += av.z * bv.z; accf[11] += av.z * bv.w;
      accf[12] += av.w * bv.x; accf[13] += av.w * bv.y; accf[14] += av.w * bv.z; accf[15] += av.w * bv.w;
    }
#pragma unroll
    for (int i = 0; i < 16; ++i) accd[i] += (double)accf[i];
    __syncthreads();
  }

#pragma unroll
  for (int i = 0; i < 4; ++i) {
    size_t rowoff = (size_t)(bm + (ty << 2) + i) * H_UNITS + bn + (tx << 2);
    float4 o;
    o.x = (float)accd[i * 4 + 0]; o.y = (float)accd[i * 4 + 1];
    o.z = (float)accd[i * 4 + 2]; o.w = (float)accd[i * 4 + 3];
    *reinterpret_cast<float4*>(C + rowoff) = o;
  }
}

// ---------------------------------------------------------------------------
// Totally-ordered sort key: XLA float total order (sign-magnitude bitcast)
// desc, index asc, packed in u64. -0.0 < +0.0 under this order, matching
// XLA's top_k comparator. key unique per element -> exact top_k semantics.
// ---------------------------------------------------------------------------
__device__ __forceinline__ unsigned long long make_key(float r, int j) {
  unsigned int u = __float_as_uint(r);
  u ^= (u & 0x80000000u) ? 0xFFFFFFFFu : 0x80000000u;
  return (((unsigned long long)u) << 14) | (unsigned long long)(16383 - j);
}

// ---------------------------------------------------------------------------
// Kernel 2: sequential inhibition scan, brute-force exact.
// One block, 1024 threads, 16 keys/thread in registers.
// fp32 recurrence with _rn intrinsics (no FMA contraction) == np float32.
// (refracted = |e|*(1-i) is never -0.0, and +0.0 ties never reach rank 64,
//  so scan top-k is comparator-convention-independent.)
// ---------------------------------------------------------------------------
__global__ __launch_bounds__(1024) void scan_brute(const float* __restrict__ enc,
                                                   float* __restrict__ inhib,
                                                   int* __restrict__ seli) {
  const int tid = threadIdx.x;
  __shared__ unsigned long long wmax[16];
  __shared__ unsigned long long s_win;
  __shared__ int wlist[64];
  __shared__ unsigned int bmap[512];

  for (int i = tid; i < H_UNITS; i += 1024) inhib[i] = 0.0f;
  __syncthreads();

  for (int t = 0; t < B_ROWS; ++t) {
    const float* erow = enc + (size_t)t * H_UNITS;

    // phase A: keys + thread-local max
    unsigned long long key[16];
    unsigned long long lmax = 0ull;
#pragma unroll
    for (int q = 0; q < 16; ++q) {
      int j = q * 1024 + tid;
      float e = erow[j];
      float i0 = inhib[j];
      float r = __fmul_rn(fabsf(e), __fsub_rn(1.0f, i0));
      unsigned long long k = make_key(r, j);
      key[q] = k;
      if (k > lmax) lmax = k;
    }
    if (tid < 512) bmap[tid] = 0u;
    __syncthreads();

    // phase B: 64 extraction rounds
    for (int round = 0; round < 64; ++round) {
      unsigned long long v = lmax;
#pragma unroll
      for (int d = 32; d >= 1; d >>= 1) {
        unsigned long long o = __shfl_down(v, d);
        if (o > v) v = o;
      }
      if ((tid & 63) == 0) wmax[tid >> 6] = v;
      __syncthreads();
      if (tid == 0) {
        unsigned long long m = wmax[0];
#pragma unroll
        for (int w = 1; w < 16; ++w)
          if (wmax[w] > m) m = wmax[w];
        s_win = m;
        int idx = 16383 - (int)(m & 0x3FFFull);
        wlist[round] = idx;
        bmap[idx >> 5] |= (1u << (idx & 31));
      }
      __syncthreads();
      unsigned long long Wk = s_win;
      if (lmax == Wk) {  // unique owner: recompute local max over keys < Wk
        unsigned long long nm = 0ull;
#pragma unroll
        for (int q = 0; q < 16; ++q) {
          unsigned long long k = key[q];
          if (k < Wk && k > nm) nm = k;
        }
        lmax = nm;
      }
    }
    __syncthreads();

    // phase C: inhibition update, np-exact: i' = rn(rn(i*0.95) + mask)
#pragma unroll
    for (int q = 0; q < 16; ++q) {
      int j = q * 1024 + tid;
      float i0 = inhib[j];
      float m = ((bmap[j >> 5] >> (j & 31)) & 1u) ? 1.0f : 0.0f;
      inhib[j] = __fadd_rn(__fmul_rn(i0, 0.95f), m);
    }
    // phase D: winners out
    if (tid < 64) seli[t * 64 + tid] = wlist[tid];
    __syncthreads();  // protect wlist/bmap reuse next step
  }
}

// ---------------------------------------------------------------------------
// Kernel 3: final top-64 over filtered = enc * mask, brute-force exact.
// KEY FIX vs rounds 0-5: non-selected positions keep the SIGN of enc
// (enc * 0.0 = ±0.0), and the key comparator is XLA total order where
// +0.0 > -0.0. Selected negative values sort below all zeros, so ~half the
// final mask comes from lowest-index POSITIVE-enc unselected positions.
// Reads its enc row into registers BEFORE overwriting (out == enc buffer).
// ---------------------------------------------------------------------------
__global__ __launch_bounds__(1024) void final_brute(const int* __restrict__ seli,
                                                    float* __restrict__ out) {
  const int row = blockIdx.x;
  const int tid = threadIdx.x;
  __shared__ unsigned long long wmax[16];
  __shared__ unsigned long long s_win;
  __shared__ int wlist[64];
  __shared__ unsigned int bmap[512];
  const float* erow = out + (size_t)row * H_UNITS;

  if (tid < 512) bmap[tid] = 0u;
  __syncthreads();
  if (tid < 64) {
    int idx = seli[row * 64 + tid];
    atomicOr(&bmap[idx >> 5], 1u << (idx & 31));
  }
  __syncthreads();

  unsigned long long key[16];
  unsigned long long lmax = 0ull;
#pragma unroll
  for (int q = 0; q < 16; ++q) {
    int j = q * 1024 + tid;
    float e = erow[j];
    bool sel = (bmap[j >> 5] >> (j & 31)) & 1u;
    // filtered = e * mask with IEEE sign semantics: unselected -> ±0.0 (sign of e)
    unsigned int eb = __float_as_uint(e);
    float f = __uint_as_float(sel ? eb : (eb & 0x80000000u));
    unsigned long long k = make_key(f, j);
    key[q] = k;
    if (k > lmax) lmax = k;
  }
  __syncthreads();

  // zero the row (keys already safe in registers)
  float4 z = make_float4(0.0f, 0.0f, 0.0f, 0.0f);
  float4* o4 = reinterpret_cast<float4*>(out + (size_t)row * H_UNITS);
  for (int i = tid; i < H_UNITS / 4; i += 1024) o4[i] = z;
  __syncthreads();

  for (int round = 0; round < 64; ++round) {
    unsigned long long v = lmax;
#pragma unroll
    for (int d = 32; d >= 1; d >>= 1) {
      unsigned long long o = __shfl_down(v, d);
      if (o > v) v = o;
    }
    if ((tid & 63) == 0) wmax[tid >> 6] = v;
    __syncthreads();
    if (tid == 0) {
      unsigned long long m = wmax[0];
#pragma unroll
      for (int w = 1; w < 16; ++w)
        if (wmax[w] > m) m = wmax[w];
      s_win = m;
      wlist[round] = 16383 - (int)(m & 0x3FFFull);
    }
    __syncthreads();
    unsigned long long Wk = s_win;
    if (lmax == Wk) {
      unsigned long long nm = 0ull;
#pragma unroll
      for (int q = 0; q < 16; ++q) {
        unsigned long long k = key[q];
        if (k < Wk && k > nm) nm = k;
      }
      lmax = nm;
    }
  }
  __syncthreads();
  if (tid < 64) out[(size_t)row * H_UNITS + wlist[tid]] = 1.0f;
}

// ---------------------------------------------------------------------------
extern "C" void kernel_launch(void* const* d_in, const int* in_sizes, int n_in,
                              void* d_out, int out_size, void* d_ws, size_t ws_size,
                              hipStream_t stream) {
  const float* inputs = (const float*)d_in[0];   // [512][2048] fp32
  const float* W = (const float*)d_in[1];        // [16384][2048] fp32
  float* out = (float*)d_out;                    // [512][16384] fp32 -- also enc scratch
  char* ws = (char*)d_ws;

  float* inhib = (float*)(ws);                   // 65,536 B
  int* seli = (int*)(ws + 65536);                // 131,072 B  (total ws: 192 KB)

  float* enc = out;  // encoding scratch lives in d_out

  gemm_kernel<<<dim3(H_UNITS / 64, B_ROWS / 64), 256, 0, stream>>>(inputs, W, enc);
  scan_brute<<<1, 1024, 0, stream>>>(enc, inhib, seli);
  final_brute<<<B_ROWS, 1024, 0, stream>>>(seli, out);
}

// Round 7
// 12226.267 us; speedup vs baseline: 2.8992x; 2.8992x over previous
//
#include <hip/hip_runtime.h>
#include <math.h>
#include <stdint.h>

// Problem constants
#define B_ROWS 512
#define H_UNITS 16384
#define K_IN 2048
#define K_SEL 64
#define QPT 16  // keys per thread = 16384 / 1024

// ---------------------------------------------------------------------------
// Kernel 1: encoding = inputs @ W^T  (fp32 mul, 64-chunk fp32 acc, fp64 chunk sum)
// C[512][16384] = A[512][2048] . W[16384][2048]^T   -- C lives in d_out
// (unchanged from the round-6 PASSING version)
// ---------------------------------------------------------------------------
__global__ __launch_bounds__(256) void gemm_kernel(const float* __restrict__ A,
                                                   const float* __restrict__ W,
                                                   float* __restrict__ C) {
  __shared__ __align__(16) float As[64][68];
  __shared__ __align__(16) float Bs[64][68];
  const int tid = threadIdx.x;
  const int tx = tid & 15, ty = tid >> 4;
  const int bm = blockIdx.y * 64, bn = blockIdx.x * 64;

  double accd[16];
#pragma unroll
  for (int i = 0; i < 16; ++i) accd[i] = 0.0;

  const float* Ab = A + (size_t)bm * K_IN;
  const float* Wb = W + (size_t)bn * K_IN;

  for (int k0 = 0; k0 < K_IN; k0 += 64) {
#pragma unroll
    for (int p = 0; p < 4; ++p) {
      int id = p * 256 + tid;
      int m = id >> 4;
      int kq = (id & 15) << 2;
      float4 a = *reinterpret_cast<const float4*>(Ab + (size_t)m * K_IN + k0 + kq);
      As[kq + 0][m] = a.x; As[kq + 1][m] = a.y; As[kq + 2][m] = a.z; As[kq + 3][m] = a.w;
      float4 b = *reinterpret_cast<const float4*>(Wb + (size_t)m * K_IN + k0 + kq);
      Bs[kq + 0][m] = b.x; Bs[kq + 1][m] = b.y; Bs[kq + 2][m] = b.z; Bs[kq + 3][m] = b.w;
    }
    __syncthreads();

    float accf[16];
#pragma unroll
    for (int i = 0; i < 16; ++i) accf[i] = 0.0f;

#pragma unroll 16
    for (int kk = 0; kk < 64; ++kk) {
      float4 av = *reinterpret_cast<const float4*>(&As[kk][ty << 2]);
      float4 bv = *reinterpret_cast<const float4*>(&Bs[kk][tx << 2]);
      accf[0]  += av.x * bv.x; accf[1]  += av.x * bv.y; accf[2]  += av.x * bv.z; accf[3]  += av.x * bv.w;
      accf[4]  += av.y * bv.x; accf[5]  += av.y * bv.y; accf[6]  += av.y * bv.z; accf[7]  += av.y * bv.w;
      accf[8]  += av.z * bv.x; accf[9]  += av.z * bv.y; accf[10] += av.z * bv.z; accf[11] += av.z * bv.w;
      accf[12] += av.w * bv.x; accf[13] += av.w * bv.y; accf[14] += av.w * bv.z; accf[15] += av.w * bv.w;
    }
#pragma unroll
    for (int i = 0; i < 16; ++i) accd[i] += (double)accf[i];
    __syncthreads();
  }

#pragma unroll
  for (int i = 0; i < 4; ++i) {
    size_t rowoff = (size_t)(bm + (ty << 2) + i) * H_UNITS + bn + (tx << 2);
    float4 o;
    o.x = (float)accd[i * 4 + 0]; o.y = (float)accd[i * 4 + 1];
    o.z = (float)accd[i * 4 + 2]; o.w = (float)accd[i * 4 + 3];
    *reinterpret_cast<float4*>(C + rowoff) = o;
  }
}

// ---------------------------------------------------------------------------
// XLA float total order as u32: monotone bitcast (sign-magnitude flip).
// -0.0 < +0.0 under this order. u32 compare == total-order float compare.
// ---------------------------------------------------------------------------
__device__ __forceinline__ unsigned int orderable(float x) {
  unsigned int u = __float_as_uint(x);
  return u ^ ((u & 0x80000000u) ? 0xFFFFFFFFu : 0x80000000u);
}

// key for the (validated) final_brute tournament: (total order desc, idx asc)
__device__ __forceinline__ unsigned long long make_key(float r, int j) {
  unsigned int u = orderable(r);
  return (((unsigned long long)u) << 14) | (unsigned long long)(16383 - j);
}

// ---------------------------------------------------------------------------
// Wave-0 suffix bucket find: given hist[64*CH], locate bucket b (counting
// from the TOP) where the descending cumulative count first reaches `need`.
// Outputs b and `above` = count of keys in buckets > b (above < need).
// ---------------------------------------------------------------------------
__device__ __forceinline__ void suffix_find(const unsigned int* hist, int CH, int need,
                                            int tid, int* s_b, int* s_above) {
  if (tid < 64) {
    unsigned int s = 0;
    for (int q = 0; q < CH; ++q) s += hist[tid * CH + q];
#pragma unroll
    for (int d = 1; d < 64; d <<= 1) {  // inclusive suffix over lanes
      unsigned int o = __shfl_down(s, d);
      if (tid + d < 64) s += o;
    }
    unsigned int snext = __shfl_down(s, 1);
    if (tid == 63) snext = 0;
    bool cross = (s >= (unsigned int)need) && (snext < (unsigned int)need);
    unsigned long long bal = __ballot(cross);
    int g = __ffsll(bal) - 1;  // unique crossing lane (incl. suffix is monotone)
    if (tid == g) {
      unsigned int acc = snext;
      int b = g * CH;
      for (int q = CH - 1; q >= 0; --q) {
        unsigned int c = hist[g * CH + q];
        if (acc + c >= (unsigned int)need) { b = g * CH + q; break; }
        acc += c;
      }
      *s_b = b; *s_above = (int)acc;
    }
  }
}

// ---------------------------------------------------------------------------
// Kernel 2: sequential inhibition scan via 3-pass radix select (exact).
// One block, 1024 threads. Inhibition lives in 16 VGPRs per thread
// (element j = q*1024+tid is thread-stationary). Per step:
//   keys o = orderable(|e|*(1-i))  [np-fp32-exact recurrence]
//   radix select 64th-largest key: 11+11+10-bit histogram passes -> exact o*
//   select o > o*  plus  (need - above) ties at o* by smallest index
//   == top-64 under (float total order desc, idx asc) == lax.top_k.
// ---------------------------------------------------------------------------
__global__ __launch_bounds__(1024) void scan_radix(const float* __restrict__ enc,
                                                   int* __restrict__ seli) {
  const int tid = threadIdx.x;
  __shared__ unsigned int hist1[2048];
  __shared__ unsigned int hist2[2048];
  __shared__ unsigned int hist3[1024];
  __shared__ unsigned int bmap[512];
  __shared__ int tielist[1024];
  __shared__ int s_b1, s_ab1, s_b2, s_ab2, s_b3, s_ab3;
  __shared__ int s_nsel, s_tiecnt;

  float iv[QPT];
#pragma unroll
  for (int q = 0; q < QPT; ++q) iv[q] = 0.0f;

  for (int t = 0; t < B_ROWS; ++t) {
    const float* erow = enc + (size_t)t * H_UNITS;
    unsigned int ok[QPT];

    // zero LDS + compute keys
    for (int i = tid; i < 2048; i += 1024) { hist1[i] = 0u; hist2[i] = 0u; }
    hist3[tid] = 0u;
    if (tid < 512) bmap[tid] = 0u;
    if (tid == 0) { s_nsel = 0; s_tiecnt = 0; }
#pragma unroll
    for (int q = 0; q < QPT; ++q) {
      int j = q * 1024 + tid;
      float e = erow[j];
      float r = __fmul_rn(fabsf(e), __fsub_rn(1.0f, iv[q]));  // np-exact
      ok[q] = orderable(r);
    }
    __syncthreads();  // B1

    // pass 1: top 11 bits
#pragma unroll
    for (int q = 0; q < QPT; ++q) atomicAdd(&hist1[ok[q] >> 21], 1u);
    __syncthreads();  // B2
    suffix_find(hist1, 32, 64, tid, &s_b1, &s_ab1);
    __syncthreads();  // B3
    const unsigned int b1 = (unsigned int)s_b1;
    const int need2 = 64 - s_ab1;

    // pass 2: middle 11 bits within bucket b1
#pragma unroll
    for (int q = 0; q < QPT; ++q)
      if ((ok[q] >> 21) == b1) atomicAdd(&hist2[(ok[q] >> 10) & 0x7FFu], 1u);
    __syncthreads();  // B4
    suffix_find(hist2, 32, need2, tid, &s_b2, &s_ab2);
    __syncthreads();  // B5
    const unsigned int pfx = (b1 << 21) | ((unsigned int)s_b2 << 10);
    const int need3 = need2 - s_ab2;

    // pass 3: low 10 bits within (b1,b2)
#pragma unroll
    for (int q = 0; q < QPT; ++q)
      if ((ok[q] & 0xFFFFFC00u) == pfx) atomicAdd(&hist3[ok[q] & 0x3FFu], 1u);
    __syncthreads();  // B6
    suffix_find(hist3, 16, need3, tid, &s_b3, &s_ab3);
    __syncthreads();  // B7
    const unsigned int ostar = pfx | (unsigned int)s_b3;  // exact 64th key value
    const int tneed = need3 - s_ab3;  // ties to take at o* (>=1), smallest idx first

    // membership (o > o*) + tie collection (o == o*)
    int* srow = seli + t * 64;
#pragma unroll
    for (int q = 0; q < QPT; ++q) {
      int j = q * 1024 + tid;
      unsigned int o = ok[q];
      if (o > ostar) {                       // strictly above: always selected
        int slot = atomicAdd(&s_nsel, 1);    // slots [0, 64-tneed)
        srow[slot] = j;
        atomicOr(&bmap[j >> 5], 1u << (j & 31));
      } else if (o == ostar) {
        int p = atomicAdd(&s_tiecnt, 1);
        if (p < 1024) tielist[p] = j;
      }
    }
    __syncthreads();  // B8

    // tie resolve: take tneed smallest indices among ties
    if (tid == 0) {
      int tc = s_tiecnt; if (tc > 1024) tc = 1024;
      for (int k = 0; k < tneed; ++k) {
        int bi = 0x7FFFFFFF, bpos = 0;
        for (int i = 0; i < tc; ++i) {
          int v = tielist[i];
          if (v < bi) { bi = v; bpos = i; }
        }
        tielist[bpos] = 0x7FFFFFFF;
        bmap[bi >> 5] |= (1u << (bi & 31));
        srow[64 - tneed + k] = bi;
      }
    }
    __syncthreads();  // B9

    // inhibition update in registers, np-exact: i' = rn(rn(i*0.95) + m)
#pragma unroll
    for (int q = 0; q < QPT; ++q) {
      int j = q * 1024 + tid;
      float m = ((bmap[j >> 5] >> (j & 31)) & 1u) ? 1.0f : 0.0f;
      iv[q] = __fadd_rn(__fmul_rn(iv[q], 0.95f), m);
    }
    __syncthreads();  // B10: bmap/scalars stable before next step's zeroing
  }
}

// ---------------------------------------------------------------------------
// Kernel 3: final top-64 over filtered = enc * mask, brute-force exact.
// Non-selected positions keep the SIGN of enc (enc * 0.0 = ±0.0) under the
// XLA total-order comparator (+0 > -0). Validated in round 6 — unchanged.
// ---------------------------------------------------------------------------
__global__ __launch_bounds__(1024) void final_brute(const int* __restrict__ seli,
                                                    float* __restrict__ out) {
  const int row = blockIdx.x;
  const int tid = threadIdx.x;
  __shared__ unsigned long long wmax[16];
  __shared__ unsigned long long s_win;
  __shared__ int wlist[64];
  __shared__ unsigned int bmap[512];
  const float* erow = out + (size_t)row * H_UNITS;

  if (tid < 512) bmap[tid] = 0u;
  __syncthreads();
  if (tid < 64) {
    int idx = seli[row * 64 + tid];
    atomicOr(&bmap[idx >> 5], 1u << (idx & 31));
  }
  __syncthreads();

  unsigned long long key[16];
  unsigned long long lmax = 0ull;
#pragma unroll
  for (int q = 0; q < 16; ++q) {
    int j = q * 1024 + tid;
    float e = erow[j];
    bool sel = (bmap[j >> 5] >> (j & 31)) & 1u;
    unsigned int eb = __float_as_uint(e);
    float f = __uint_as_float(sel ? eb : (eb & 0x80000000u));  // ±0 keeps sign
    unsigned long long k = make_key(f, j);
    key[q] = k;
    if (k > lmax) lmax = k;
  }
  __syncthreads();

  float4 z = make_float4(0.0f, 0.0f, 0.0f, 0.0f);
  float4* o4 = reinterpret_cast<float4*>(out + (size_t)row * H_UNITS);
  for (int i = tid; i < H_UNITS / 4; i += 1024) o4[i] = z;
  __syncthreads();

  for (int round = 0; round < 64; ++round) {
    unsigned long long v = lmax;
#pragma unroll
    for (int d = 32; d >= 1; d >>= 1) {
      unsigned long long o = __shfl_down(v, d);
      if (o > v) v = o;
    }
    if ((tid & 63) == 0) wmax[tid >> 6] = v;
    __syncthreads();
    if (tid == 0) {
      unsigned long long m = wmax[0];
#pragma unroll
      for (int w = 1; w < 16; ++w)
        if (wmax[w] > m) m = wmax[w];
      s_win = m;
      wlist[round] = 16383 - (int)(m & 0x3FFFull);
    }
    __syncthreads();
    unsigned long long Wk = s_win;
    if (lmax == Wk) {
      unsigned long long nm = 0ull;
#pragma unroll
      for (int q = 0; q < 16; ++q) {
        unsigned long long k = key[q];
        if (k < Wk && k > nm) nm = k;
      }
      lmax = nm;
    }
  }
  __syncthreads();
  if (tid < 64) out[(size_t)row * H_UNITS + wlist[tid]] = 1.0f;
}

// ---------------------------------------------------------------------------
extern "C" void kernel_launch(void* const* d_in, const int* in_sizes, int n_in,
                              void* d_out, int out_size, void* d_ws, size_t ws_size,
                              hipStream_t stream) {
  const float* inputs = (const float*)d_in[0];   // [512][2048] fp32
  const float* W = (const float*)d_in[1];        // [16384][2048] fp32
  float* out = (float*)d_out;                    // [512][16384] fp32 -- also enc scratch
  char* ws = (char*)d_ws;

  int* seli = (int*)(ws);                        // 131,072 B (total ws use: 128 KB)

  float* enc = out;  // encoding scratch lives in d_out

  gemm_kernel<<<dim3(H_UNITS / 64, B_ROWS / 64), 256, 0, stream>>>(inputs, W, enc);
  scan_radix<<<1, 1024, 0, stream>>>(enc, seli);
  final_brute<<<B_ROWS, 1024, 0, stream>>>(seli, out);
}